// Round 3
// baseline (942.652 us; speedup 1.0000x reference)
//
#include <hip/hip_runtime.h>

#define HD 128      // H*D = IN = 128
#define GPAD 132    // LDS row pad: 132 words = 528B (16B aligned, stride mod 32 = 4 -> 4-way max)

// ---------------- Phase 1: three projections  O[n,128] = X[n,128] @ W[128,128]^T ----------------
__global__ __launch_bounds__(256) void k_gemm3(
    const float* __restrict__ q, const float* __restrict__ k, const float* __restrict__ v,
    const float* __restrict__ wq, const float* __restrict__ wk, const float* __restrict__ wv,
    float* __restrict__ qh, float* __restrict__ kh, float* __restrict__ vh, int n)
{
    __shared__ float wlds[128 * GPAD];
    const float* X; const float* W; float* O;
    if (blockIdx.y == 0)      { X = q; W = wq; O = qh; }
    else if (blockIdx.y == 1) { X = k; W = wk; O = kh; }
    else                      { X = v; W = wv; O = vh; }

    int tid = threadIdx.x;
    // stage W (64KB) into LDS, padded rows
    for (int idx = tid; idx < 128 * 32; idx += 256) {
        int r = idx >> 5, c4 = (idx & 31) << 2;
        *(float4*)&wlds[r * GPAD + c4] = *(const float4*)&W[r * 128 + c4];
    }
    __syncthreads();

    int col  = tid & 127;
    int row0 = blockIdx.x * 16 + (tid >> 7) * 8;
    float acc[8] = {0.f,0.f,0.f,0.f,0.f,0.f,0.f,0.f};

    for (int k4 = 0; k4 < 128; k4 += 4) {
        float4 w = *(const float4*)&wlds[col * GPAD + k4];
        #pragma unroll
        for (int i = 0; i < 8; i++) {
            int r = row0 + i;
            if (r < n) {
                float4 x = *(const float4*)&X[r * 128 + k4];
                acc[i] += w.x * x.x + w.y * x.y + w.z * x.z + w.w * x.w;
            }
        }
    }
    #pragma unroll
    for (int i = 0; i < 8; i++) {
        int r = row0 + i;
        if (r < n) O[r * 128 + col] = acc[i];
    }
}

// ---------------- Phase 2: CSR build ----------------
__global__ void k_hist(const int* __restrict__ dst, int* __restrict__ count, int e)
{
    int i = blockIdx.x * blockDim.x + threadIdx.x;
    if (i < e) atomicAdd(&count[dst[i]], 1);
}

__global__ __launch_bounds__(1024) void k_scan(const int* __restrict__ count,
                                               int* __restrict__ offsets,
                                               int* __restrict__ cursor, int n)
{
    __shared__ int sums[1024];
    int t = threadIdx.x;
    int chunk = (n + 1023) >> 10;
    int beg = t * chunk;
    int end = min(beg + chunk, n);
    int s = 0;
    for (int i = beg; i < end; i++) s += count[i];
    sums[t] = s;
    __syncthreads();
    // Hillis-Steele inclusive scan over 1024 partials
    for (int off = 1; off < 1024; off <<= 1) {
        int val = (t >= off) ? sums[t - off] : 0;
        __syncthreads();
        sums[t] += val;
        __syncthreads();
    }
    int run = (t == 0) ? 0 : sums[t - 1];
    for (int i = beg; i < end; i++) {
        offsets[i] = run;
        cursor[i]  = run;
        run += count[i];
    }
    if (t == 1023) offsets[n] = sums[1023];
}

__global__ void k_scatter(const int* __restrict__ src, const int* __restrict__ dst,
                          int* __restrict__ cursor, int* __restrict__ csr_src, int e)
{
    int i = blockIdx.x * blockDim.x + threadIdx.x;
    if (i < e) {
        int p = atomicAdd(&cursor[dst[i]], 1);
        csr_src[p] = src[i];
    }
}

// ---------------- Phase 3: per-node gather (1 wave = 1 node) ----------------
// lane -> (h = lane>>3, j = lane&7), handles d = {2j, 2j+1}; h*16+2j == 2*lane
__global__ __launch_bounds__(256) void k_gather(
    const float* __restrict__ qh, const float* __restrict__ kh, const float* __restrict__ vh,
    const int* __restrict__ offsets, const int* __restrict__ csr_src,
    float* __restrict__ out, int n)
{
    int wave = threadIdx.x >> 6;
    int lane = threadIdx.x & 63;
    int v = blockIdx.x * 4 + wave;
    if (v >= n) return;

    float2 qv = *(const float2*)&qh[v * HD + lane * 2];
    int beg = offsets[v], end = offsets[v + 1];

    float ax = 0.f, ay = 0.f, zz = 0.f;
    int e = beg;
    // 2-wide manual unroll for load-latency overlap
    for (; e + 1 < end; e += 2) {
        int u0 = csr_src[e];
        int u1 = csr_src[e + 1];
        float2 k0 = *(const float2*)&kh[u0 * HD + lane * 2];
        float2 v0 = *(const float2*)&vh[u0 * HD + lane * 2];
        float2 k1 = *(const float2*)&kh[u1 * HD + lane * 2];
        float2 v1 = *(const float2*)&vh[u1 * HD + lane * 2];
        float p0 = k0.x * qv.x + k0.y * qv.y;
        float p1 = k1.x * qv.x + k1.y * qv.y;
        p0 += __shfl_xor(p0, 1); p1 += __shfl_xor(p1, 1);
        p0 += __shfl_xor(p0, 2); p1 += __shfl_xor(p1, 2);
        p0 += __shfl_xor(p0, 4); p1 += __shfl_xor(p1, 4);
        float s0 = fminf(fmaxf(p0 * 0.25f, -5.f), 5.f);
        float s1 = fminf(fmaxf(p1 * 0.25f, -5.f), 5.f);
        float a0 = __expf(s0);
        float a1 = __expf(s1);
        ax += a0 * v0.x + a1 * v1.x;
        ay += a0 * v0.y + a1 * v1.y;
        zz += a0 + a1;
    }
    for (; e < end; ++e) {
        int u = csr_src[e];
        float2 kk = *(const float2*)&kh[u * HD + lane * 2];
        float2 vv = *(const float2*)&vh[u * HD + lane * 2];
        float p = kk.x * qv.x + kk.y * qv.y;
        p += __shfl_xor(p, 1);
        p += __shfl_xor(p, 2);
        p += __shfl_xor(p, 4);
        float sc = fminf(fmaxf(p * 0.25f, -5.f), 5.f);
        float a = __expf(sc);
        ax += a * vv.x;
        ay += a * vv.y;
        zz += a;
    }
    float inv = 1.f / zz;
    float2 o;
    o.x = ax * inv;
    o.y = ay * inv;
    *(float2*)&out[v * HD + lane * 2] = o;
}

// ---------------- launch ----------------
extern "C" void kernel_launch(void* const* d_in, const int* in_sizes, int n_in,
                              void* d_out, int out_size, void* d_ws, size_t ws_size,
                              hipStream_t stream)
{
    const float* query = (const float*)d_in[0];
    const float* key   = (const float*)d_in[1];
    const float* value = (const float*)d_in[2];
    const float* WQ    = (const float*)d_in[3];
    const float* WK    = (const float*)d_in[4];
    const float* WV    = (const float*)d_in[5];
    const int*   esrc  = (const int*)d_in[6];
    const int*   edst  = (const int*)d_in[7];
    int n = in_sizes[0] / HD;
    int E = in_sizes[6];

    char* ws = (char*)d_ws;
    size_t off = 0;
    auto carve = [&](size_t bytes) -> void* {
        void* p = ws + off;
        off += (bytes + 255) & ~size_t(255);
        return p;
    };
    float* qh      = (float*)carve((size_t)n * HD * 4);
    float* kh      = (float*)carve((size_t)n * HD * 4);
    float* vh      = (float*)carve((size_t)n * HD * 4);
    int*   count   = (int*)carve((size_t)n * 4);
    int*   offsets = (int*)carve((size_t)(n + 1) * 4);
    int*   cursor  = (int*)carve((size_t)n * 4);
    int*   csr_src = (int*)carve((size_t)E * 4);
    (void)ws_size;

    hipMemsetAsync(count, 0, (size_t)n * 4, stream);

    dim3 ggrid((n + 15) / 16, 3);
    k_gemm3<<<ggrid, 256, 0, stream>>>(query, key, value, WQ, WK, WV, qh, kh, vh, n);

    int eblocks = (E + 255) / 256;
    k_hist<<<eblocks, 256, 0, stream>>>(edst, count, E);
    k_scan<<<1, 1024, 0, stream>>>(count, offsets, cursor, n);
    k_scatter<<<eblocks, 256, 0, stream>>>(esrc, edst, cursor, csr_src, E);

    k_gather<<<(n + 3) / 4, 256, 0, stream>>>(qh, kh, vh, offsets, csr_src,
                                              (float*)d_out, n);
}

// Round 4
// 347.760 us; speedup vs baseline: 2.7106x; 2.7106x over previous
//
#include <hip/hip_runtime.h>

#define HD 128      // H*D = IN = 128

typedef short bf16x8 __attribute__((ext_vector_type(8)));
typedef float f32x4  __attribute__((ext_vector_type(4)));

static __device__ __forceinline__ unsigned short f2bf_bits(float f) {
    union { float f; unsigned u; } x; x.f = f;
    unsigned r = x.u + 0x7FFF + ((x.u >> 16) & 1);   // RNE
    return (unsigned short)(r >> 16);
}

// ---------------- Phase 0: convert W (3 x 128x128 f32) to bf16 ----------------
__global__ void k_cvtW(const float* __restrict__ wq, const float* __restrict__ wk,
                       const float* __restrict__ wv, short* __restrict__ wb)
{
    int t = blockIdx.x * blockDim.x + threadIdx.x;   // one float4 per thread
    if (t >= 3 * 16384 / 4) return;
    int flat = t * 4;
    int m = flat >> 14;          // /16384
    int off = flat & 16383;
    const float* W = (m == 0) ? wq : (m == 1) ? wk : wv;
    float4 v = *(const float4*)(W + off);
    short4 s;
    s.x = (short)f2bf_bits(v.x);
    s.y = (short)f2bf_bits(v.y);
    s.z = (short)f2bf_bits(v.z);
    s.w = (short)f2bf_bits(v.w);
    *(short4*)(wb + flat) = s;
}

// ---------------- Phase 1: projections via bf16 MFMA ----------------
// O[n,128] = X[n,128] @ W[128,128]^T.  Wave = 16 rows x 128 cols.
// A-frag: lane l holds X[row0 + (l&15)][kk*32 + (l>>4)*8 .. +8]  (8 contig k)
// B-frag: lane l holds W[nt*16 + (l&15)][kk*32 + (l>>4)*8 .. +8] (16B dwordx4, L1/L2-hit)
// C/D:    col = lane&15, row = (lane>>4)*4 + i   [verified layout]
__global__ __launch_bounds__(256) void k_proj(
    const float* __restrict__ q, const float* __restrict__ k, const float* __restrict__ v,
    const short* __restrict__ wb,
    float* __restrict__ qh, float* __restrict__ kh, float* __restrict__ vh,
    int n, int ntiles, int gx)
{
    int m = blockIdx.y;
    const float* X = (m == 0) ? q : (m == 1) ? k : v;
    float*       O = (m == 0) ? qh : (m == 1) ? kh : vh;
    const short* W = wb + m * 16384;

    int wave = threadIdx.x >> 6, lane = threadIdx.x & 63;
    int lm = lane & 15, lg = lane >> 4;
    const short* wp = W + lm * HD + lg * 8;

    for (int tile = blockIdx.x; tile < ntiles; tile += gx) {
        int row0 = tile * 64 + wave * 16;
        int arow = row0 + lm; if (arow >= n) arow = n - 1;    // clamp loads; stores guarded
        const float* xp = X + (size_t)arow * HD + lg * 8;

        bf16x8 a[4];
        #pragma unroll
        for (int kk = 0; kk < 4; kk++) {
            float4 p0 = *(const float4*)(xp + kk * 32);
            float4 p1 = *(const float4*)(xp + kk * 32 + 4);
            bf16x8 t;
            t[0] = (short)f2bf_bits(p0.x); t[1] = (short)f2bf_bits(p0.y);
            t[2] = (short)f2bf_bits(p0.z); t[3] = (short)f2bf_bits(p0.w);
            t[4] = (short)f2bf_bits(p1.x); t[5] = (short)f2bf_bits(p1.y);
            t[6] = (short)f2bf_bits(p1.z); t[7] = (short)f2bf_bits(p1.w);
            a[kk] = t;
        }

        f32x4 acc[8];
        #pragma unroll
        for (int nt = 0; nt < 8; nt++) { f32x4 z = {0.f, 0.f, 0.f, 0.f}; acc[nt] = z; }

        #pragma unroll
        for (int nt = 0; nt < 8; nt++) {
            #pragma unroll
            for (int kk = 0; kk < 4; kk++) {
                bf16x8 b = *(const bf16x8*)(wp + nt * 16 * HD + kk * 32);
                acc[nt] = __builtin_amdgcn_mfma_f32_16x16x32_bf16(a[kk], b, acc[nt], 0, 0, 0);
            }
        }

        #pragma unroll
        for (int nt = 0; nt < 8; nt++) {
            #pragma unroll
            for (int i = 0; i < 4; i++) {
                int r = row0 + lg * 4 + i;
                if (r < n) O[(size_t)r * HD + nt * 16 + lm] = acc[nt][i];
            }
        }
    }
}

// ---------------- Phase 2: CSR build ----------------
__global__ void k_hist(const int* __restrict__ dst, int* __restrict__ count, int e)
{
    int i = blockIdx.x * blockDim.x + threadIdx.x;
    if (i < e) atomicAdd(&count[dst[i]], 1);
}

__global__ __launch_bounds__(1024) void k_scan(const int* __restrict__ count,
                                               int* __restrict__ offsets,
                                               int* __restrict__ cursor, int n)
{
    __shared__ int sums[1024];
    int t = threadIdx.x;
    int chunk = (n + 1023) >> 10;
    int beg = t * chunk;
    int end = min(beg + chunk, n);
    int s = 0;
    for (int i = beg; i < end; i++) s += count[i];
    sums[t] = s;
    __syncthreads();
    for (int off = 1; off < 1024; off <<= 1) {
        int val = (t >= off) ? sums[t - off] : 0;
        __syncthreads();
        sums[t] += val;
        __syncthreads();
    }
    int run = (t == 0) ? 0 : sums[t - 1];
    for (int i = beg; i < end; i++) {
        offsets[i] = run;
        cursor[i]  = run;
        run += count[i];
    }
    if (t == 1023) offsets[n] = sums[1023];
}

__global__ void k_scatter(const int* __restrict__ src, const int* __restrict__ dst,
                          int* __restrict__ cursor, int* __restrict__ csr_src, int e)
{
    int i = blockIdx.x * blockDim.x + threadIdx.x;
    if (i < e) {
        int p = atomicAdd(&cursor[dst[i]], 1);
        csr_src[p] = src[i];
    }
}

// ---------------- Phase 3: per-node gather (1 wave = 1 node) ----------------
__global__ __launch_bounds__(256) void k_gather(
    const float* __restrict__ qh, const float* __restrict__ kh, const float* __restrict__ vh,
    const int* __restrict__ offsets, const int* __restrict__ csr_src,
    float* __restrict__ out, int n)
{
    int wave = threadIdx.x >> 6;
    int lane = threadIdx.x & 63;
    int v = blockIdx.x * 4 + wave;
    if (v >= n) return;

    float2 qv = *(const float2*)&qh[v * HD + lane * 2];
    int beg = offsets[v], end = offsets[v + 1];

    float ax = 0.f, ay = 0.f, zz = 0.f;
    int e = beg;
    for (; e + 1 < end; e += 2) {
        int u0 = csr_src[e];
        int u1 = csr_src[e + 1];
        float2 k0 = *(const float2*)&kh[u0 * HD + lane * 2];
        float2 v0 = *(const float2*)&vh[u0 * HD + lane * 2];
        float2 k1 = *(const float2*)&kh[u1 * HD + lane * 2];
        float2 v1 = *(const float2*)&vh[u1 * HD + lane * 2];
        float p0 = k0.x * qv.x + k0.y * qv.y;
        float p1 = k1.x * qv.x + k1.y * qv.y;
        p0 += __shfl_xor(p0, 1); p1 += __shfl_xor(p1, 1);
        p0 += __shfl_xor(p0, 2); p1 += __shfl_xor(p1, 2);
        p0 += __shfl_xor(p0, 4); p1 += __shfl_xor(p1, 4);
        float s0 = fminf(fmaxf(p0 * 0.25f, -5.f), 5.f);
        float s1 = fminf(fmaxf(p1 * 0.25f, -5.f), 5.f);
        float a0 = __expf(s0);
        float a1 = __expf(s1);
        ax += a0 * v0.x + a1 * v1.x;
        ay += a0 * v0.y + a1 * v1.y;
        zz += a0 + a1;
    }
    for (; e < end; ++e) {
        int u = csr_src[e];
        float2 kk = *(const float2*)&kh[u * HD + lane * 2];
        float2 vv = *(const float2*)&vh[u * HD + lane * 2];
        float p = kk.x * qv.x + kk.y * qv.y;
        p += __shfl_xor(p, 1);
        p += __shfl_xor(p, 2);
        p += __shfl_xor(p, 4);
        float sc = fminf(fmaxf(p * 0.25f, -5.f), 5.f);
        float a = __expf(sc);
        ax += a * vv.x;
        ay += a * vv.y;
        zz += a;
    }
    float inv = 1.f / zz;
    float2 o;
    o.x = ax * inv;
    o.y = ay * inv;
    *(float2*)&out[v * HD + lane * 2] = o;
}

// ---------------- launch ----------------
extern "C" void kernel_launch(void* const* d_in, const int* in_sizes, int n_in,
                              void* d_out, int out_size, void* d_ws, size_t ws_size,
                              hipStream_t stream)
{
    const float* query = (const float*)d_in[0];
    const float* key   = (const float*)d_in[1];
    const float* value = (const float*)d_in[2];
    const float* WQ    = (const float*)d_in[3];
    const float* WK    = (const float*)d_in[4];
    const float* WV    = (const float*)d_in[5];
    const int*   esrc  = (const int*)d_in[6];
    const int*   edst  = (const int*)d_in[7];
    int n = in_sizes[0] / HD;
    int E = in_sizes[6];

    char* ws = (char*)d_ws;
    size_t off = 0;
    auto carve = [&](size_t bytes) -> void* {
        void* p = ws + off;
        off += (bytes + 255) & ~size_t(255);
        return p;
    };
    float* qh      = (float*)carve((size_t)n * HD * 4);
    float* kh      = (float*)carve((size_t)n * HD * 4);
    float* vh      = (float*)carve((size_t)n * HD * 4);
    short* wb      = (short*)carve((size_t)3 * 16384 * 2);
    int*   count   = (int*)carve((size_t)n * 4);
    int*   offsets = (int*)carve((size_t)(n + 1) * 4);
    int*   cursor  = (int*)carve((size_t)n * 4);
    int*   csr_src = (int*)carve((size_t)E * 4);
    (void)ws_size;

    hipMemsetAsync(count, 0, (size_t)n * 4, stream);

    k_cvtW<<<48, 256, 0, stream>>>(WQ, WK, WV, wb);

    int ntiles = (n + 63) / 64;
    int gx = (ntiles + 1) / 2;          // 2 tiles per block
    dim3 pgrid(gx, 3);
    k_proj<<<pgrid, 256, 0, stream>>>(query, key, value, wb, qh, kh, vh, n, ntiles, gx);

    int eblocks = (E + 255) / 256;
    k_hist<<<eblocks, 256, 0, stream>>>(edst, count, E);
    k_scan<<<1, 1024, 0, stream>>>(count, offsets, cursor, n);
    k_scatter<<<eblocks, 256, 0, stream>>>(esrc, edst, cursor, csr_src, E);

    k_gather<<<(n + 3) / 4, 256, 0, stream>>>(qh, kh, vh, offsets, csr_src,
                                              (float*)d_out, n);
}

// Round 5
// 216.870 us; speedup vs baseline: 4.3466x; 1.6035x over previous
//
#include <hip/hip_runtime.h>

#define HD 128      // H*D = IN = 128

typedef short bf16x8 __attribute__((ext_vector_type(8)));
typedef float f32x4  __attribute__((ext_vector_type(4)));

static __device__ __forceinline__ unsigned short f2bf_bits(float f) {
    union { float f; unsigned u; } x; x.f = f;
    unsigned r = x.u + 0x7FFF + ((x.u >> 16) & 1);   // RNE
    return (unsigned short)(r >> 16);
}
static __device__ __forceinline__ float bf2f(unsigned short s) {
    union { unsigned u; float f; } x; x.u = ((unsigned)s) << 16;
    return x.f;
}

// ---------------- Phase 0: convert W (3 x 128x128 f32) to bf16 ----------------
__global__ void k_cvtW(const float* __restrict__ wq, const float* __restrict__ wk,
                       const float* __restrict__ wv, short* __restrict__ wb)
{
    int t = blockIdx.x * blockDim.x + threadIdx.x;   // one float4 per thread
    if (t >= 3 * 16384 / 4) return;
    int flat = t * 4;
    int m = flat >> 14;          // /16384
    int off = flat & 16383;
    const float* W = (m == 0) ? wq : (m == 1) ? wk : wv;
    float4 v = *(const float4*)(W + off);
    short4 s;
    s.x = (short)f2bf_bits(v.x);
    s.y = (short)f2bf_bits(v.y);
    s.z = (short)f2bf_bits(v.z);
    s.w = (short)f2bf_bits(v.w);
    *(short4*)(wb + flat) = s;
}

// ---------------- Phase 1: projections via bf16 MFMA ----------------
// m=0: Qh f32 [n,128].  m=1: K -> kvb[u][0..128) bf16.  m=2: V -> kvb[u][128..256) bf16.
// A-frag: lane l holds X[row0+(l&15)][kk*32+(l>>4)*8 ..+8]; B-frag from bf16 W (L1/L2-hit).
// C/D: col=lane&15, row=(lane>>4)*4+i  [verified layout]
__global__ __launch_bounds__(256) void k_proj(
    const float* __restrict__ q, const float* __restrict__ k, const float* __restrict__ v,
    const short* __restrict__ wb,
    float* __restrict__ qh, short* __restrict__ kvb,
    int n, int ntiles, int gx)
{
    int m = blockIdx.y;
    const float* X = (m == 0) ? q : (m == 1) ? k : v;
    const short* W = wb + m * 16384;

    int wave = threadIdx.x >> 6, lane = threadIdx.x & 63;
    int lm = lane & 15, lg = lane >> 4;
    const short* wp = W + lm * HD + lg * 8;

    for (int tile = blockIdx.x; tile < ntiles; tile += gx) {
        int row0 = tile * 64 + wave * 16;
        int arow = row0 + lm; if (arow >= n) arow = n - 1;    // clamp loads; stores guarded
        const float* xp = X + (size_t)arow * HD + lg * 8;

        bf16x8 a[4];
        #pragma unroll
        for (int kk = 0; kk < 4; kk++) {
            float4 p0 = *(const float4*)(xp + kk * 32);
            float4 p1 = *(const float4*)(xp + kk * 32 + 4);
            bf16x8 t;
            t[0] = (short)f2bf_bits(p0.x); t[1] = (short)f2bf_bits(p0.y);
            t[2] = (short)f2bf_bits(p0.z); t[3] = (short)f2bf_bits(p0.w);
            t[4] = (short)f2bf_bits(p1.x); t[5] = (short)f2bf_bits(p1.y);
            t[6] = (short)f2bf_bits(p1.z); t[7] = (short)f2bf_bits(p1.w);
            a[kk] = t;
        }

        f32x4 acc[8];
        #pragma unroll
        for (int nt = 0; nt < 8; nt++) { f32x4 z = {0.f, 0.f, 0.f, 0.f}; acc[nt] = z; }

        #pragma unroll
        for (int nt = 0; nt < 8; nt++) {
            #pragma unroll
            for (int kk = 0; kk < 4; kk++) {
                bf16x8 b = *(const bf16x8*)(wp + nt * 16 * HD + kk * 32);
                acc[nt] = __builtin_amdgcn_mfma_f32_16x16x32_bf16(a[kk], b, acc[nt], 0, 0, 0);
            }
        }

        if (m == 0) {
            #pragma unroll
            for (int nt = 0; nt < 8; nt++)
                #pragma unroll
                for (int i = 0; i < 4; i++) {
                    int r = row0 + lg * 4 + i;
                    if (r < n) qh[(size_t)r * HD + nt * 16 + lm] = acc[nt][i];
                }
        } else {
            short* base = kvb + ((m == 1) ? 0 : HD);
            #pragma unroll
            for (int nt = 0; nt < 8; nt++)
                #pragma unroll
                for (int i = 0; i < 4; i++) {
                    int r = row0 + lg * 4 + i;
                    if (r < n) base[(size_t)r * 256 + nt * 16 + lm] =
                        (short)f2bf_bits(acc[nt][i]);
                }
        }
    }
}

// ---------------- Phase 2: CSR build ----------------
__global__ void k_hist(const int* __restrict__ dst, int* __restrict__ count, int e)
{
    int i = blockIdx.x * blockDim.x + threadIdx.x;
    if (i < e) atomicAdd(&count[dst[i]], 1);
}

// Wave-aggregated region allocator: replaces the single-block scan.
// Regions are allocated in arbitrary (wave-arrival) order; gather uses offsets[v]+count[v].
__global__ __launch_bounds__(256) void k_alloc(const int* __restrict__ count,
                                               int* __restrict__ offsets,
                                               int* __restrict__ cursor,
                                               int* __restrict__ total, int n)
{
    int i = blockIdx.x * blockDim.x + threadIdx.x;
    int lane = threadIdx.x & 63;
    int c = (i < n) ? count[i] : 0;
    int pre = c;
    #pragma unroll
    for (int d = 1; d < 64; d <<= 1) {
        int t = __shfl_up(pre, d);
        if (lane >= d) pre += t;
    }
    int base = 0;
    if (lane == 63) base = atomicAdd(total, pre);
    base = __shfl(base, 63);
    int off = base + pre - c;
    if (i < n) { offsets[i] = off; cursor[i] = off; }
}

__global__ void k_scatter(const int* __restrict__ src, const int* __restrict__ dst,
                          int* __restrict__ cursor, int* __restrict__ csr_src, int e)
{
    int i = blockIdx.x * blockDim.x + threadIdx.x;
    if (i < e) {
        int p = atomicAdd(&cursor[dst[i]], 1);
        csr_src[p] = src[i];
    }
}

// ---------------- Phase 3: per-node gather (1 wave = 1 node) ----------------
// kv[u] = 256 bf16: [0..128)=K row, [128..256)=V row. One 8B load/lane/edge.
// Lane l<32: K dims 4l..4l+3, head = l>>2 (4-lane groups). Lane 32+j: V dims 4j..4j+3.
// shfl_xor(a,32) carries the per-head weight K-half -> V-half.
__global__ __launch_bounds__(256) void k_gather(
    const float* __restrict__ qh, const short* __restrict__ kvb,
    const int* __restrict__ offsets, const int* __restrict__ count,
    const int* __restrict__ csr_src, float* __restrict__ out, int n)
{
    int wave = threadIdx.x >> 6;
    int lane = threadIdx.x & 63;
    int v = blockIdx.x * 4 + wave;
    if (v >= n) return;
    int j = lane & 31;

    float4 qv = *(const float4*)&qh[(size_t)v * HD + 4 * j];
    int beg = offsets[v], end = beg + count[v];

    float4 acc = {0.f, 0.f, 0.f, 0.f};
    float z = 0.f;

    int e = beg;
    for (; e + 1 < end; e += 2) {
        int u0 = csr_src[e];
        int u1 = csr_src[e + 1];
        ushort4 kv0 = *(const ushort4*)&kvb[(size_t)u0 * 256 + 4 * lane];
        ushort4 kv1 = *(const ushort4*)&kvb[(size_t)u1 * 256 + 4 * lane];
        float x00 = bf2f(kv0.x), x01 = bf2f(kv0.y), x02 = bf2f(kv0.z), x03 = bf2f(kv0.w);
        float x10 = bf2f(kv1.x), x11 = bf2f(kv1.y), x12 = bf2f(kv1.z), x13 = bf2f(kv1.w);
        float p0 = x00 * qv.x + x01 * qv.y + x02 * qv.z + x03 * qv.w;
        float p1 = x10 * qv.x + x11 * qv.y + x12 * qv.z + x13 * qv.w;
        p0 += __shfl_xor(p0, 1); p1 += __shfl_xor(p1, 1);
        p0 += __shfl_xor(p0, 2); p1 += __shfl_xor(p1, 2);
        float a0 = __expf(fminf(fmaxf(p0 * 0.25f, -5.f), 5.f));
        float a1 = __expf(fminf(fmaxf(p1 * 0.25f, -5.f), 5.f));
        float av0 = __shfl_xor(a0, 32);
        float av1 = __shfl_xor(a1, 32);
        z += a0 + a1;                       // meaningful on K-half lanes only
        acc.x += av0 * x00 + av1 * x10;     // meaningful on V-half lanes only
        acc.y += av0 * x01 + av1 * x11;
        acc.z += av0 * x02 + av1 * x12;
        acc.w += av0 * x03 + av1 * x13;
    }
    for (; e < end; ++e) {
        int u = csr_src[e];
        ushort4 kv = *(const ushort4*)&kvb[(size_t)u * 256 + 4 * lane];
        float x0 = bf2f(kv.x), x1 = bf2f(kv.y), x2 = bf2f(kv.z), x3 = bf2f(kv.w);
        float p = x0 * qv.x + x1 * qv.y + x2 * qv.z + x3 * qv.w;
        p += __shfl_xor(p, 1);
        p += __shfl_xor(p, 2);
        float a = __expf(fminf(fmaxf(p * 0.25f, -5.f), 5.f));
        float av = __shfl_xor(a, 32);
        z += a;
        acc.x += av * x0; acc.y += av * x1; acc.z += av * x2; acc.w += av * x3;
    }

    float zz = __shfl_xor(z, 32);           // V-half gets K-half's denominator
    if (lane >= 32) {
        float inv = 1.f / zz;
        float4 o = { acc.x * inv, acc.y * inv, acc.z * inv, acc.w * inv };
        *(float4*)&out[(size_t)v * HD + 4 * j] = o;
    }
}

// ---------------- launch ----------------
extern "C" void kernel_launch(void* const* d_in, const int* in_sizes, int n_in,
                              void* d_out, int out_size, void* d_ws, size_t ws_size,
                              hipStream_t stream)
{
    const float* query = (const float*)d_in[0];
    const float* key   = (const float*)d_in[1];
    const float* value = (const float*)d_in[2];
    const float* WQ    = (const float*)d_in[3];
    const float* WK    = (const float*)d_in[4];
    const float* WV    = (const float*)d_in[5];
    const int*   esrc  = (const int*)d_in[6];
    const int*   edst  = (const int*)d_in[7];
    int n = in_sizes[0] / HD;
    int E = in_sizes[6];

    char* ws = (char*)d_ws;
    size_t off = 0;
    auto carve = [&](size_t bytes) -> void* {
        void* p = ws + off;
        off += (bytes + 255) & ~size_t(255);
        return p;
    };
    float* qh      = (float*)carve((size_t)n * HD * 4);
    short* kvb     = (short*)carve((size_t)n * 256 * 2);
    short* wb      = (short*)carve((size_t)3 * 16384 * 2);
    int*   count   = (int*)carve((size_t)(n + 1) * 4);   // [n] = total cursor
    int*   offsets = (int*)carve((size_t)n * 4);
    int*   cursor  = (int*)carve((size_t)n * 4);
    int*   csr_src = (int*)carve((size_t)E * 4);
    (void)ws_size;

    hipMemsetAsync(count, 0, (size_t)(n + 1) * 4, stream);

    k_cvtW<<<48, 256, 0, stream>>>(WQ, WK, WV, wb);

    int ntiles = (n + 63) / 64;
    int gx = (ntiles + 1) / 2;          // 2 tiles per block
    dim3 pgrid(gx, 3);
    k_proj<<<pgrid, 256, 0, stream>>>(query, key, value, wb, qh, kvb, n, ntiles, gx);

    int eblocks = (E + 255) / 256;
    k_hist<<<eblocks, 256, 0, stream>>>(edst, count, E);
    k_alloc<<<(n + 255) / 256, 256, 0, stream>>>(count, offsets, cursor, count + n, n);
    k_scatter<<<eblocks, 256, 0, stream>>>(esrc, edst, cursor, csr_src, E);

    k_gather<<<(n + 3) / 4, 256, 0, stream>>>(qh, kvb, offsets, count, csr_src,
                                              (float*)d_out, n);
}

// Round 6
// 190.889 us; speedup vs baseline: 4.9382x; 1.1361x over previous
//
#include <hip/hip_runtime.h>

#define HD 128      // H*D = IN = 128

typedef short bf16x8 __attribute__((ext_vector_type(8)));
typedef float f32x4  __attribute__((ext_vector_type(4)));

static __device__ __forceinline__ unsigned short f2bf_bits(float f) {
    union { float f; unsigned u; } x; x.f = f;
    unsigned r = x.u + 0x7FFF + ((x.u >> 16) & 1);   // RNE
    return (unsigned short)(r >> 16);
}
static __device__ __forceinline__ float bf2f(unsigned short s) {
    union { unsigned u; float f; } x; x.u = ((unsigned)s) << 16;
    return x.f;
}

// ---------------- Phase 0: convert W to bf16 + zero count[] (fused) ----------------
__global__ __launch_bounds__(256) void k_pre(
    const float* __restrict__ wq, const float* __restrict__ wk,
    const float* __restrict__ wv, short* __restrict__ wb,
    int* __restrict__ count, int n1)
{
    int t = blockIdx.x * blockDim.x + threadIdx.x;
    int nthr = gridDim.x * blockDim.x;
    for (int i = t; i < 3 * 16384 / 4; i += nthr) {
        int flat = i * 4;
        int m = flat >> 14;
        int off = flat & 16383;
        const float* W = (m == 0) ? wq : (m == 1) ? wk : wv;
        float4 v = *(const float4*)(W + off);
        short4 s;
        s.x = (short)f2bf_bits(v.x);
        s.y = (short)f2bf_bits(v.y);
        s.z = (short)f2bf_bits(v.z);
        s.w = (short)f2bf_bits(v.w);
        *(short4*)(wb + flat) = s;
    }
    for (int i = t; i < n1; i += nthr) count[i] = 0;
}

// ---------------- Phase 1: projections via bf16 MFMA, + edge histogram fused ----------------
// y=0: Qh f32.  y=1: K -> kvb[u][0..128).  y=2: V -> kvb[u][128..256).  y=3: histogram.
__global__ __launch_bounds__(256) void k_proj(
    const float* __restrict__ q, const float* __restrict__ k, const float* __restrict__ v,
    const short* __restrict__ wb,
    float* __restrict__ qh, short* __restrict__ kvb,
    const int* __restrict__ edst, int* __restrict__ count, int E,
    int n, int ntiles, int gx)
{
    int m = blockIdx.y;
    if (m == 3) {   // histogram slice: overlaps with MFMA blocks
        int nthr = gx * 256;
        for (int i = blockIdx.x * 256 + threadIdx.x; i < E; i += nthr)
            atomicAdd(&count[edst[i]], 1);
        return;
    }
    const float* X = (m == 0) ? q : (m == 1) ? k : v;
    const short* W = wb + m * 16384;

    int wave = threadIdx.x >> 6, lane = threadIdx.x & 63;
    int lm = lane & 15, lg = lane >> 4;
    const short* wp = W + lm * HD + lg * 8;

    for (int tile = blockIdx.x; tile < ntiles; tile += gx) {
        int row0 = tile * 64 + wave * 16;
        int arow = row0 + lm; if (arow >= n) arow = n - 1;    // clamp loads; stores guarded
        const float* xp = X + (size_t)arow * HD + lg * 8;

        bf16x8 a[4];
        #pragma unroll
        for (int kk = 0; kk < 4; kk++) {
            float4 p0 = *(const float4*)(xp + kk * 32);
            float4 p1 = *(const float4*)(xp + kk * 32 + 4);
            bf16x8 t;
            t[0] = (short)f2bf_bits(p0.x); t[1] = (short)f2bf_bits(p0.y);
            t[2] = (short)f2bf_bits(p0.z); t[3] = (short)f2bf_bits(p0.w);
            t[4] = (short)f2bf_bits(p1.x); t[5] = (short)f2bf_bits(p1.y);
            t[6] = (short)f2bf_bits(p1.z); t[7] = (short)f2bf_bits(p1.w);
            a[kk] = t;
        }

        f32x4 acc[8];
        #pragma unroll
        for (int nt = 0; nt < 8; nt++) { f32x4 z = {0.f, 0.f, 0.f, 0.f}; acc[nt] = z; }

        #pragma unroll
        for (int nt = 0; nt < 8; nt++) {
            #pragma unroll
            for (int kk = 0; kk < 4; kk++) {
                bf16x8 b = *(const bf16x8*)(wp + nt * 16 * HD + kk * 32);
                acc[nt] = __builtin_amdgcn_mfma_f32_16x16x32_bf16(a[kk], b, acc[nt], 0, 0, 0);
            }
        }

        if (m == 0) {
            #pragma unroll
            for (int nt = 0; nt < 8; nt++)
                #pragma unroll
                for (int i = 0; i < 4; i++) {
                    int r = row0 + lg * 4 + i;
                    if (r < n) qh[(size_t)r * HD + nt * 16 + lm] = acc[nt][i];
                }
        } else {
            short* base = kvb + ((m == 1) ? 0 : HD);
            #pragma unroll
            for (int nt = 0; nt < 8; nt++)
                #pragma unroll
                for (int i = 0; i < 4; i++) {
                    int r = row0 + lg * 4 + i;
                    if (r < n) base[(size_t)r * 256 + nt * 16 + lm] =
                        (short)f2bf_bits(acc[nt][i]);
                }
        }
    }
}

// ---------------- Phase 2: CSR region allocation + scatter ----------------
// Wave-aggregated allocator; regions in arbitrary order, gather uses offsets[v]+count[v].
__global__ __launch_bounds__(256) void k_alloc(const int* __restrict__ count,
                                               int* __restrict__ offsets,
                                               int* __restrict__ cursor,
                                               int* __restrict__ total, int n)
{
    int i = blockIdx.x * blockDim.x + threadIdx.x;
    int lane = threadIdx.x & 63;
    int c = (i < n) ? count[i] : 0;
    int pre = c;
    #pragma unroll
    for (int d = 1; d < 64; d <<= 1) {
        int t = __shfl_up(pre, d);
        if (lane >= d) pre += t;
    }
    int base = 0;
    if (lane == 63) base = atomicAdd(total, pre);
    base = __shfl(base, 63);
    int off = base + pre - c;
    if (i < n) { offsets[i] = off; cursor[i] = off; }
}

__global__ void k_scatter(const int* __restrict__ src, const int* __restrict__ dst,
                          int* __restrict__ cursor, int* __restrict__ csr_src, int e)
{
    int i = blockIdx.x * blockDim.x + threadIdx.x;
    if (i < e) {
        int p = atomicAdd(&cursor[dst[i]], 1);
        csr_src[p] = src[i];
    }
}

// ---------------- Phase 3: per-node gather (1 wave = 1 node), 4-wide pipelined ----------------
// kv[u] = 256 bf16: [0..128)=K, [128..256)=V. One 8B load/lane/edge.
// Lane l<32: K dims 4l..4l+3 (head = l>>2). Lane 32+j: V dims 4j..4j+3.
// shfl_xor(a,32) carries per-head weight K-half -> V-half.
__global__ __launch_bounds__(256) void k_gather(
    const float* __restrict__ qh, const short* __restrict__ kvb,
    const int* __restrict__ offsets, const int* __restrict__ count,
    const int* __restrict__ csr_src, float* __restrict__ out, int n)
{
    int wave = threadIdx.x >> 6;
    int lane = threadIdx.x & 63;
    int v = blockIdx.x * 4 + wave;
    if (v >= n) return;
    int j = lane & 31;

    float4 qv = *(const float4*)&qh[(size_t)v * HD + 4 * j];
    int beg = offsets[v], end = beg + count[v];

    float4 acc = {0.f, 0.f, 0.f, 0.f};
    float z = 0.f;

    int e = beg;
    for (; e + 3 < end; e += 4) {
        int u0 = csr_src[e];
        int u1 = csr_src[e + 1];
        int u2 = csr_src[e + 2];
        int u3 = csr_src[e + 3];
        ushort4 kv0 = *(const ushort4*)&kvb[(size_t)u0 * 256 + 4 * lane];
        ushort4 kv1 = *(const ushort4*)&kvb[(size_t)u1 * 256 + 4 * lane];
        ushort4 kv2 = *(const ushort4*)&kvb[(size_t)u2 * 256 + 4 * lane];
        ushort4 kv3 = *(const ushort4*)&kvb[(size_t)u3 * 256 + 4 * lane];
        float x00 = bf2f(kv0.x), x01 = bf2f(kv0.y), x02 = bf2f(kv0.z), x03 = bf2f(kv0.w);
        float x10 = bf2f(kv1.x), x11 = bf2f(kv1.y), x12 = bf2f(kv1.z), x13 = bf2f(kv1.w);
        float x20 = bf2f(kv2.x), x21 = bf2f(kv2.y), x22 = bf2f(kv2.z), x23 = bf2f(kv2.w);
        float x30 = bf2f(kv3.x), x31 = bf2f(kv3.y), x32 = bf2f(kv3.z), x33 = bf2f(kv3.w);
        float p0 = x00 * qv.x + x01 * qv.y + x02 * qv.z + x03 * qv.w;
        float p1 = x10 * qv.x + x11 * qv.y + x12 * qv.z + x13 * qv.w;
        float p2 = x20 * qv.x + x21 * qv.y + x22 * qv.z + x23 * qv.w;
        float p3 = x30 * qv.x + x31 * qv.y + x32 * qv.z + x33 * qv.w;
        p0 += __shfl_xor(p0, 1); p1 += __shfl_xor(p1, 1);
        p2 += __shfl_xor(p2, 1); p3 += __shfl_xor(p3, 1);
        p0 += __shfl_xor(p0, 2); p1 += __shfl_xor(p1, 2);
        p2 += __shfl_xor(p2, 2); p3 += __shfl_xor(p3, 2);
        float a0 = __expf(fminf(fmaxf(p0 * 0.25f, -5.f), 5.f));
        float a1 = __expf(fminf(fmaxf(p1 * 0.25f, -5.f), 5.f));
        float a2 = __expf(fminf(fmaxf(p2 * 0.25f, -5.f), 5.f));
        float a3 = __expf(fminf(fmaxf(p3 * 0.25f, -5.f), 5.f));
        float av0 = __shfl_xor(a0, 32);
        float av1 = __shfl_xor(a1, 32);
        float av2 = __shfl_xor(a2, 32);
        float av3 = __shfl_xor(a3, 32);
        z += (a0 + a1) + (a2 + a3);              // K-half lanes
        acc.x += av0 * x00 + av1 * x10 + av2 * x20 + av3 * x30;   // V-half lanes
        acc.y += av0 * x01 + av1 * x11 + av2 * x21 + av3 * x31;
        acc.z += av0 * x02 + av1 * x12 + av2 * x22 + av3 * x32;
        acc.w += av0 * x03 + av1 * x13 + av2 * x23 + av3 * x33;
    }
    for (; e < end; ++e) {
        int u = csr_src[e];
        ushort4 kv = *(const ushort4*)&kvb[(size_t)u * 256 + 4 * lane];
        float x0 = bf2f(kv.x), x1 = bf2f(kv.y), x2 = bf2f(kv.z), x3 = bf2f(kv.w);
        float p = x0 * qv.x + x1 * qv.y + x2 * qv.z + x3 * qv.w;
        p += __shfl_xor(p, 1);
        p += __shfl_xor(p, 2);
        float a = __expf(fminf(fmaxf(p * 0.25f, -5.f), 5.f));
        float av = __shfl_xor(a, 32);
        z += a;
        acc.x += av * x0; acc.y += av * x1; acc.z += av * x2; acc.w += av * x3;
    }

    float zz = __shfl_xor(z, 32);           // V-half gets K-half's denominator
    if (lane >= 32) {
        float inv = 1.f / zz;
        float4 o = { acc.x * inv, acc.y * inv, acc.z * inv, acc.w * inv };
        *(float4*)&out[(size_t)v * HD + 4 * j] = o;
    }
}

// ---------------- launch ----------------
extern "C" void kernel_launch(void* const* d_in, const int* in_sizes, int n_in,
                              void* d_out, int out_size, void* d_ws, size_t ws_size,
                              hipStream_t stream)
{
    const float* query = (const float*)d_in[0];
    const float* key   = (const float*)d_in[1];
    const float* value = (const float*)d_in[2];
    const float* WQ    = (const float*)d_in[3];
    const float* WK    = (const float*)d_in[4];
    const float* WV    = (const float*)d_in[5];
    const int*   esrc  = (const int*)d_in[6];
    const int*   edst  = (const int*)d_in[7];
    int n = in_sizes[0] / HD;
    int E = in_sizes[6];

    char* ws = (char*)d_ws;
    size_t off = 0;
    auto carve = [&](size_t bytes) -> void* {
        void* p = ws + off;
        off += (bytes + 255) & ~size_t(255);
        return p;
    };
    float* qh      = (float*)carve((size_t)n * HD * 4);
    short* kvb     = (short*)carve((size_t)n * 256 * 2);
    short* wb      = (short*)carve((size_t)3 * 16384 * 2);
    int*   count   = (int*)carve((size_t)(n + 1) * 4);   // [n] = total cursor
    int*   offsets = (int*)carve((size_t)n * 4);
    int*   cursor  = (int*)carve((size_t)n * 4);
    int*   csr_src = (int*)carve((size_t)E * 4);
    (void)ws_size;

    k_pre<<<64, 256, 0, stream>>>(WQ, WK, WV, wb, count, n + 1);

    int ntiles = (n + 63) / 64;
    int gx = (ntiles + 1) / 2;          // 2 tiles per block
    dim3 pgrid(gx, 4);                  // y=0..2 proj, y=3 histogram
    k_proj<<<pgrid, 256, 0, stream>>>(query, key, value, wb, qh, kvb,
                                      edst, count, E, n, ntiles, gx);

    k_alloc<<<(n + 255) / 256, 256, 0, stream>>>(count, offsets, cursor, count + n, n);

    int eblocks = (E + 255) / 256;
    k_scatter<<<eblocks, 256, 0, stream>>>(esrc, edst, cursor, csr_src, E);

    k_gather<<<(n + 3) / 4, 256, 0, stream>>>(qh, kvb, offsets, count, csr_src,
                                              (float*)d_out, n);
}